// Round 3
// baseline (134.853 us; speedup 1.0000x reference)
//
#include <hip/hip_runtime.h>

#define MAX_ITEMS 100000
constexpr int B = 4096;
constexpr int D = 512;
constexpr long long ACT_ELEMS  = (long long)B * D;               // 2097152
constexpr long long HIST_ELEMS = (long long)(MAX_ITEMS + 1) * D; // 51200512
// d_out layout: [0, ACT) activations, [ACT] loss, [ACT+1, ACT+1+HIST) new_history.
// new_history base = float index ACT+1 (4B-aligned only). outh+3 IS 16B-aligned,
// so dst float4 group g covers hist floats [3+4g, 6+4g].

// ---------------------------------------------------------------------------
// Kernel 1: history -> out[ACT+1..). Both sides dwordx4:
//   load src groups float4-aligned; dst group g = {src[g].w, src[g+1].xyz};
//   src[g+1] comes from lane+1 via __shfl_down; lane 63 patches via 3 scalar
//   loads (always in-bounds: group NG exists fully in src).
// ---------------------------------------------------------------------------
template <int KU>
__global__ void copy_hist_kernel(const float* __restrict__ hist,
                                 float* __restrict__ out) {
    constexpr long long NG = (HIST_ELEMS - 3) / 4; // 12800127 dst float4 groups
    float* __restrict__ outh = out + ACT_ELEMS + 1;
    const float4* __restrict__ src = reinterpret_cast<const float4*>(hist);
    const int lane = threadIdx.x & 63;
    const long long chunk = (long long)blockDim.x * KU;

    for (long long c = blockIdx.x; c * chunk < NG; c += gridDim.x) {
        const long long g0 = c * chunk + threadIdx.x;
        float4 v[KU];
        #pragma unroll
        for (int k = 0; k < KU; ++k) {
            const long long g = g0 + (long long)k * blockDim.x;
            if (g <= NG) v[k] = src[g];   // group NG is valid src memory
        }
        #pragma unroll
        for (int k = 0; k < KU; ++k) {
            const long long g = g0 + (long long)k * blockDim.x;
            // shuffles unconditional: all lanes participate; v[k] is valid
            // whenever the consumer lane's store guard passes (g monotone in lane)
            float nx = __shfl_down(v[k].x, 1);
            float ny = __shfl_down(v[k].y, 1);
            float nz = __shfl_down(v[k].z, 1);
            if (g < NG) {
                if (lane == 63) { // g+1 lives in the next wave: patch scalar
                    nx = hist[4 * (g + 1) + 0];
                    ny = hist[4 * (g + 1) + 1];
                    nz = hist[4 * (g + 1) + 2];
                }
                *reinterpret_cast<float4*>(outh + 3 + 4 * g) =
                    make_float4(v[k].w, nx, ny, nz);
            }
        }
    }
    if (blockIdx.x == 0 && threadIdx.x == 0) {
        outh[0] = hist[0];
        outh[1] = hist[1];
        outh[2] = hist[2];
        outh[HIST_ELEMS - 1] = hist[HIST_ELEMS - 1]; // row 100000: never updated
    }
}

// ---------------------------------------------------------------------------
// Kernel 2: one wave per sample. Copies the act row to out (fused passthrough),
// gathers old row from ORIGINAL history input, wave-reduces sum of squared
// diff -> partial[s], scatters EMA update into new_history with atomicAdd
// (duplicate ids must accumulate). Must run AFTER copy_hist (stream order).
// ---------------------------------------------------------------------------
__global__ void update_kernel(const float* __restrict__ act,
                              const float* __restrict__ hist,
                              const int* __restrict__ samples,
                              float* __restrict__ out,
                              float* __restrict__ partial) {
    const int s    = blockIdx.x;
    const int lane = threadIdx.x; // 0..63

    const float4* __restrict__ arow = reinterpret_cast<const float4*>(act + (long long)s * D);
    float4* __restrict__ aout = reinterpret_cast<float4*>(out + (long long)s * D);
    const float4 a0 = arow[lane];
    const float4 a1 = arow[lane + 64];
    aout[lane]      = a0;   // activations passthrough (unconditional)
    aout[lane + 64] = a1;

    const int id = samples[s];
    const bool active = (id > 0) && (id < MAX_ITEMS);

    float sumsq = 0.0f;
    if (active) {
        const float4* __restrict__ orow =
            reinterpret_cast<const float4*>(hist + (long long)id * D);
        float* __restrict__ newh = out + ACT_ELEMS + 1 + (long long)id * D;
        const float4 o0 = orow[lane];
        const float4 o1 = orow[lane + 64];

        {
            const float dx = a0.x - o0.x, dy = a0.y - o0.y;
            const float dz = a0.z - o0.z, dw = a0.w - o0.w;
            sumsq += dx * dx + dy * dy + dz * dz + dw * dw;
            const int e = lane * 4;
            atomicAdd(newh + e + 0, 0.1f * dx);
            atomicAdd(newh + e + 1, 0.1f * dy);
            atomicAdd(newh + e + 2, 0.1f * dz);
            atomicAdd(newh + e + 3, 0.1f * dw);
        }
        {
            const float dx = a1.x - o1.x, dy = a1.y - o1.y;
            const float dz = a1.z - o1.z, dw = a1.w - o1.w;
            sumsq += dx * dx + dy * dy + dz * dz + dw * dw;
            const int e = (lane + 64) * 4;
            atomicAdd(newh + e + 0, 0.1f * dx);
            atomicAdd(newh + e + 1, 0.1f * dy);
            atomicAdd(newh + e + 2, 0.1f * dz);
            atomicAdd(newh + e + 3, 0.1f * dw);
        }
    }
    #pragma unroll
    for (int off = 32; off; off >>= 1)
        sumsq += __shfl_down(sumsq, off);
    if (lane == 0) partial[s] = sumsq; // masked rows contribute exactly 0
}

// ---------------------------------------------------------------------------
// Kernel 3: deterministic single-block reduction of 4096 partials -> loss.
// ---------------------------------------------------------------------------
__global__ void loss_kernel(const float* __restrict__ partial,
                            const int* __restrict__ iters,
                            float* __restrict__ out) {
    __shared__ float sm[256];
    const int t = threadIdx.x;
    float s = 0.0f;
    for (int i = t; i < B; i += 256) s += partial[i];
    sm[t] = s;
    __syncthreads();
    #pragma unroll
    for (int w = 128; w; w >>= 1) {
        if (t < w) sm[t] += sm[t + w];
        __syncthreads();
    }
    if (t == 0) {
        const float it = (float)iters[0];
        const float wr = (float)(1.0 / 1000.0)   * it;
        const float cr = (float)(1.0 / 100000.0) * it;
        const float weight = 0.1f * wr / (1.0f + wr) / (1.0f + cr);
        out[ACT_ELEMS] = (sm[0] / (float)D / (float)B) * weight;
    }
}

extern "C" void kernel_launch(void* const* d_in, const int* in_sizes, int n_in,
                              void* d_out, int out_size, void* d_ws, size_t ws_size,
                              hipStream_t stream) {
    const float* act     = (const float*)d_in[0];
    const float* hist    = (const float*)d_in[1];
    const int*   samples = (const int*)d_in[2];
    const int*   iters   = (const int*)d_in[3];
    float* out     = (float*)d_out;
    float* partial = (float*)d_ws; // B*4 = 16 KiB scratch

    copy_hist_kernel<8><<<2048, 256, 0, stream>>>(hist, out);
    update_kernel<<<B, 64, 0, stream>>>(act, hist, samples, out, partial);
    loss_kernel<<<1, 256, 0, stream>>>(partial, iters, out);
}